// Round 3
// baseline (294.069 us; speedup 1.0000x reference)
//
#include <hip/hip_runtime.h>
#include <hip/hip_bf16.h>

typedef __attribute__((ext_vector_type(8))) short short8;
typedef __attribute__((ext_vector_type(4))) float f32x4;
typedef unsigned short u16;
typedef unsigned int u32;

// ---------------- workspace layout (bytes) ----------------
#define OFF_XT      0u          // x NHWC bf16: 4*64*64*256  = 8388608 B
#define OFF_OM      8388608u    // offsets fp32: 16384*32*4  = 2097152 B
#define OFF_Y       10485760u   // mdcn out NHWC bf16: 16384*128*2 = 4194304 B
#define OFF_Y2      14680064u   // deconv out NHWC bf16: 65536*128*2 = 16777216 B
#define OFF_BOFF    31457280u   // B_off_T  [32][2304] bf16  = 147456 B
#define OFF_BDCN    31604736u   // B_dcn_T  [128][2304] bf16 = 589824 B
#define OFF_BUP     32194560u   // B_up_T   [4][128][512] bf16 = 524288 B
#define OFF_STATS   32718848u   // stats1 sum/ss [256] + stats2 [256] f32 = 2048 B
#define OFF_BN1     32720896u   // float2[128]
#define OFF_BN2     32721920u   // float2[128]

__device__ __forceinline__ float lo2f(u32 u){ u32 v = u << 16; float f; __builtin_memcpy(&f, &v, 4); return f; }
__device__ __forceinline__ float hi2f(u32 u){ u32 v = u & 0xffff0000u; float f; __builtin_memcpy(&f, &v, 4); return f; }
__device__ __forceinline__ float b2f(u16 v){ u32 u = ((u32)v) << 16; float f; __builtin_memcpy(&f, &u, 4); return f; }
__device__ __forceinline__ u16 f2b(float f){ __hip_bfloat16 h = __float2bfloat16(f); u16 r; __builtin_memcpy(&r, &h, 2); return r; }

__device__ __forceinline__ f32x4 mfma16(short8 a, short8 b, f32x4 c){
  return __builtin_amdgcn_mfma_f32_16x16x32_bf16(a, b, c, 0, 0, 0);
}

// ---------------- weight reorganization (f32 -> bf16) ----------------
__global__ __launch_bounds__(256) void prep_kernel(const float* __restrict__ w_off,
                                                   const float* __restrict__ w_dcn,
                                                   const float* __restrict__ w_up,
                                                   u16* __restrict__ Boff,
                                                   u16* __restrict__ Bdcn,
                                                   u16* __restrict__ Bup){
  int i = blockIdx.x * 256 + threadIdx.x;
  if (i < 32*2304){
    int o = i / 2304, kk = i % 2304, tap = kk >> 8, c = kk & 255;
    int ky = tap / 3, kx = tap - ky*3;
    u16 v = 0;
    if (o < 27) v = f2b(w_off[((o*256 + c)*3 + ky)*3 + kx]);
    Boff[i] = v;
  }
  if (i < 128*2304){
    int o = i / 2304, kk = i % 2304, tap = kk >> 8, c = kk & 255;
    int ky = tap / 3, kx = tap - ky*3;
    Bdcn[i] = f2b(w_dcn[((o*256 + c)*3 + ky)*3 + kx]);
  }
  if (i < 4*128*512){
    int pp = i / (128*512), r = i % (128*512);
    int o = r >> 9, kk = r & 511, tapd = kk >> 7, c = kk & 127;
    int py = pp >> 1, px = pp & 1, dy = tapd >> 1, dx = tapd & 1;
    Bup[i] = f2b(w_up[((c*128 + o)*4 + (3-(py+2*dy)))*4 + (3-(px+2*dx))]);
  }
}

// ---------------- x NCHW f32 -> NHWC bf16 ----------------
__global__ __launch_bounds__(256) void transpose_kernel(const float* __restrict__ x, u16* __restrict__ xt){
  __shared__ u16 Ls[64][65];
  int blk = blockIdx.x;                 // 1024 = 4b * 64h * 4cb
  int cb = blk & 3, h = (blk >> 2) & 63, b = blk >> 8;
  int t = threadIdx.x;
  int c0 = cb * 64;
  for (int i = 0; i < 16; i++){
    int idx = t + i*256;
    int c = idx >> 6, w = idx & 63;
    Ls[c][w] = f2b(x[((b*256 + c0 + c)*64 + h)*64 + w]);
  }
  __syncthreads();
  for (int i = 0; i < 16; i++){
    int idx = t + i*256;
    int w = idx >> 6, cc = idx & 63;
    xt[(((b*64 + h)*64 + w) << 8) + c0 + cc] = Ls[cc][w];
  }
}

// ---------------- stage 1: offset conv (M=16384, N=32, K=2304) ----------------
__global__ __launch_bounds__(256) void convoff_kernel(const u16* __restrict__ xt,
                                                      const u16* __restrict__ Boff,
                                                      const float* __restrict__ b_off,
                                                      float* __restrict__ om){
  __shared__ alignas(16) u16 As[32*40];
  __shared__ alignas(16) u16 Bs[32*40];
  int blk = blockIdx.x;                 // 512 = 4b * 64h * 2
  int w0 = (blk & 1) * 32, h = (blk >> 1) & 63, b = blk >> 7;
  int t = threadIdx.x;
  int wid = t >> 6, lane = t & 63, ln = lane & 15, qd = lane >> 4;
  int msub = wid & 1, nsub = wid >> 1;
  f32x4 acc = {0.f,0.f,0.f,0.f};
  int apx = t >> 3, aco = (t & 7) * 4;  // A: 32px x 32c, 4 elems/thread
  int bo = t >> 2, bks = (t & 3) * 8;   // B: 32o x 32k, t<128

  for (int s = 0; s < 72; s++){
    int tap = s >> 3, c0 = (s & 7) * 32;
    int ky = tap / 3, kx = tap - ky*3;
    __syncthreads();
    {
      int y = h + ky - 1, xw = w0 + apx + kx - 1;
      uint2 v = make_uint2(0u, 0u);
      if ((u32)y < 64u && (u32)xw < 64u)
        v = *(const uint2*)(xt + (((b*64 + y)*64 + xw) << 8) + c0 + aco);
      *(uint2*)(As + apx*40 + aco) = v;
    }
    if (t < 128){
      uint4 v = *(const uint4*)(Boff + bo*2304 + s*32 + bks);
      *(uint4*)(Bs + bo*40 + bks) = v;
    }
    __syncthreads();
    short8 a  = *(const short8*)(As + (msub*16 + ln)*40 + qd*8);
    short8 bb = *(const short8*)(Bs + (nsub*16 + ln)*40 + qd*8);
    acc = mfma16(a, bb, acc);
  }
  int n = nsub*16 + ln;
  if (n < 27){
    float bias = b_off[n];
    for (int r = 0; r < 4; r++){
      int row = msub*16 + qd*4 + r;
      int pix = (b*64 + h)*64 + w0 + row;
      om[pix*32 + n] = acc[r] + bias;
    }
  }
}

// ---------------- stage 2: modulated deformable conv (M=16384, N=128, K=2304) ----------------
__global__ __launch_bounds__(256) void mdcn_kernel(const u16* __restrict__ xt,
                                                   const float* __restrict__ om,
                                                   const u16* __restrict__ Bdcn,
                                                   const float* __restrict__ b_dcn,
                                                   u16* __restrict__ yb,
                                                   float* __restrict__ stats1){
  __shared__ alignas(16) u16 As[32*40];
  __shared__ alignas(16) u16 Bs[128*40];
  __shared__ alignas(16) float Ys[32*132];
  int blk = blockIdx.x;                 // 512
  int w0 = (blk & 1) * 32, h = (blk >> 1) & 63, b = blk >> 7;
  int t = threadIdx.x;
  int wid = t >> 6, lane = t & 63, ln = lane & 15, qd = lane >> 4;
  f32x4 acc[2][2];
  for (int m = 0; m < 2; m++) for (int n2 = 0; n2 < 2; n2++) acc[m][n2] = (f32x4){0.f,0.f,0.f,0.f};
  int apx = t >> 3, aco = (t & 7) * 4;
  int P = (b*64 + h)*64 + w0 + apx;
  int bo = t >> 1, bks = (t & 1) * 16;

  for (int k = 0; k < 9; k++){
    int ky = k / 3, kx = k - ky*3;
    float dy = om[P*32 + 2*k];
    float dx = om[P*32 + 2*k + 1];
    float mk = 1.f / (1.f + __expf(-om[P*32 + 18 + k]));
    float ysf = (float)(h - 1 + ky) + dy;
    float xsf = (float)(w0 + apx - 1 + kx) + dx;
    float y0f = floorf(ysf), x0f = floorf(xsf);
    float ly = ysf - y0f, lx = xsf - x0f;
    int y0 = (int)y0f, x0i = (int)x0f;
    float w00 = (1.f-ly)*(1.f-lx)*mk, w01 = (1.f-ly)*lx*mk;
    float w10 = ly*(1.f-lx)*mk,       w11 = ly*lx*mk;
    bool okY0 = (u32)y0 < 64u, okY1 = (u32)(y0+1) < 64u;
    bool okX0 = (u32)x0i < 64u, okX1 = (u32)(x0i+1) < 64u;
    int a00 = ((b*64 + y0)*64 + x0i) << 8;
    int a01 = a00 + 256, a10 = a00 + (64 << 8), a11 = a10 + 256;
    bool ok00 = okY0 && okX0, ok01 = okY0 && okX1, ok10 = okY1 && okX0, ok11 = okY1 && okX1;

    for (int s2 = 0; s2 < 8; s2++){
      int c0 = s2 * 32;
      __syncthreads();
      {
        float v0 = 0.f, v1 = 0.f, v2 = 0.f, v3 = 0.f;
        #define GATHER(ok, base, wgt) do { if (ok){ \
          uint2 uu = *(const uint2*)(xt + (base) + c0 + aco); \
          v0 = fmaf((wgt), lo2f(uu.x), v0); v1 = fmaf((wgt), hi2f(uu.x), v1); \
          v2 = fmaf((wgt), lo2f(uu.y), v2); v3 = fmaf((wgt), hi2f(uu.y), v3); } } while(0)
        GATHER(ok00, a00, w00);
        GATHER(ok01, a01, w01);
        GATHER(ok10, a10, w10);
        GATHER(ok11, a11, w11);
        #undef GATHER
        uint2 pv;
        pv.x = (u32)f2b(v0) | ((u32)f2b(v1) << 16);
        pv.y = (u32)f2b(v2) | ((u32)f2b(v3) << 16);
        *(uint2*)(As + apx*40 + aco) = pv;
      }
      {
        uint4 vB0 = *(const uint4*)(Bdcn + bo*2304 + k*256 + c0 + bks);
        uint4 vB1 = *(const uint4*)(Bdcn + bo*2304 + k*256 + c0 + bks + 8);
        *(uint4*)(Bs + bo*40 + bks) = vB0;
        *(uint4*)(Bs + bo*40 + bks + 8) = vB1;
      }
      __syncthreads();
      short8 a0 = *(const short8*)(As + (ln)*40 + qd*8);
      short8 a1 = *(const short8*)(As + (16 + ln)*40 + qd*8);
      short8 b0 = *(const short8*)(Bs + (wid*32 + ln)*40 + qd*8);
      short8 b1 = *(const short8*)(Bs + (wid*32 + 16 + ln)*40 + qd*8);
      acc[0][0] = mfma16(a0, b0, acc[0][0]);
      acc[0][1] = mfma16(a0, b1, acc[0][1]);
      acc[1][0] = mfma16(a1, b0, acc[1][0]);
      acc[1][1] = mfma16(a1, b1, acc[1][1]);
    }
  }
  __syncthreads();
  {
    float bias0 = b_dcn[wid*32 + ln];
    float bias1 = b_dcn[wid*32 + 16 + ln];
    for (int m = 0; m < 2; m++)
      for (int n2 = 0; n2 < 2; n2++)
        for (int r = 0; r < 4; r++)
          Ys[(m*16 + qd*4 + r)*132 + wid*32 + n2*16 + ln] = acc[m][n2][r] + (n2 ? bias1 : bias0);
  }
  __syncthreads();
  {
    int px2 = t & 31, og = (t >> 5) * 16;
    int Pw = (b*64 + h)*64 + w0 + px2;
    u32 r[8];
    for (int e = 0; e < 8; e++){
      u32 lo = f2b(Ys[px2*132 + og + 2*e]);
      u32 hi = f2b(Ys[px2*132 + og + 2*e + 1]);
      r[e] = lo | (hi << 16);
    }
    *(uint4*)(yb + Pw*128 + og)     = make_uint4(r[0], r[1], r[2], r[3]);
    *(uint4*)(yb + Pw*128 + og + 8) = make_uint4(r[4], r[5], r[6], r[7]);
  }
  if (t < 128){
    float s = 0.f, ss = 0.f;
    for (int j = 0; j < 32; j++){
      float v = Ys[j*132 + t];
      s += v; ss += v*v;
    }
    atomicAdd(&stats1[t], s);
    atomicAdd(&stats1[128 + t], ss);
  }
}

// ---------------- BN stats finalize (shared by BN1/BN2) ----------------
__global__ __launch_bounds__(128) void bnfin_kernel(const float* __restrict__ stats,
                                                    const float* __restrict__ gamma,
                                                    const float* __restrict__ beta,
                                                    float2* __restrict__ bn,
                                                    float invN){
  int o = threadIdx.x;
  float mean = stats[o] * invN;
  float var  = stats[128 + o] * invN - mean*mean;
  float inv  = rsqrtf(var + 1e-5f);
  float sc   = gamma[o] * inv;
  bn[o] = make_float2(sc, beta[o] - mean * sc);
}

// ---------------- stage 4: transposed conv (per x-parity GEMM, K=512) ----------------
__global__ __launch_bounds__(256) void deconv_kernel(const u16* __restrict__ yb,
                                                     const float2* __restrict__ bn1,
                                                     const u16* __restrict__ Bup,
                                                     u16* __restrict__ y2,
                                                     float* __restrict__ stats2){
  __shared__ alignas(16) u16 As[64*40];
  __shared__ alignas(16) u16 Bs[128*40];
  __shared__ alignas(16) float Ys[64*132];
  __shared__ float2 BNs[128];
  int blk = blockIdx.x;                 // 1024 = 4b * 128y * 2parx
  int parx = blk & 1, yy = (blk >> 1) & 127, b = blk >> 8;
  int pary = yy & 1;
  int hs = (yy - 2 + pary) / 2;         // exact (numerator even), may be -1
  int t = threadIdx.x;
  int wid = t >> 6, lane = t & 63, ln = lane & 15, qd = lane >> 4;
  if (t < 128) BNs[t] = bn1[t];
  f32x4 acc[4][2];
  for (int m = 0; m < 4; m++) for (int n2 = 0; n2 < 2; n2++) acc[m][n2] = (f32x4){0.f,0.f,0.f,0.f};
  int aj = t >> 2, acs = (t & 3) * 8;
  int bo = t >> 1, bks = (t & 1) * 16;
  int Bbase = ((pary*2 + parx) * 128) * 512;

  for (int s = 0; s < 16; s++){
    int tapd = s >> 2, c0 = (s & 3) * 32;
    int dyy = tapd >> 1, dxx = tapd & 1;
    __syncthreads();
    {
      int hh = hs + dyy, ww = aj - 1 + parx + dxx;
      u32 r0 = 0, r1 = 0, r2 = 0, r3 = 0;
      if ((u32)hh < 64u && (u32)ww < 64u){
        uint4 u = *(const uint4*)(yb + (((b*64 + hh)*64 + ww) << 7) + c0 + acs);
        float f[8];
        f[0] = lo2f(u.x); f[1] = hi2f(u.x); f[2] = lo2f(u.y); f[3] = hi2f(u.y);
        f[4] = lo2f(u.z); f[5] = hi2f(u.z); f[6] = lo2f(u.w); f[7] = hi2f(u.w);
        u16 p[8];
        for (int e = 0; e < 8; e++){
          float2 sc = BNs[c0 + acs + e];
          p[e] = f2b(fmaxf(0.f, fmaf(sc.x, f[e], sc.y)));
        }
        r0 = (u32)p[0] | ((u32)p[1] << 16);
        r1 = (u32)p[2] | ((u32)p[3] << 16);
        r2 = (u32)p[4] | ((u32)p[5] << 16);
        r3 = (u32)p[6] | ((u32)p[7] << 16);
      }
      *(uint4*)(As + aj*40 + acs) = make_uint4(r0, r1, r2, r3);
    }
    {
      uint4 vB0 = *(const uint4*)(Bup + Bbase + bo*512 + tapd*128 + c0 + bks);
      uint4 vB1 = *(const uint4*)(Bup + Bbase + bo*512 + tapd*128 + c0 + bks + 8);
      *(uint4*)(Bs + bo*40 + bks) = vB0;
      *(uint4*)(Bs + bo*40 + bks + 8) = vB1;
    }
    __syncthreads();
    short8 b0 = *(const short8*)(Bs + (wid*32 + ln)*40 + qd*8);
    short8 b1 = *(const short8*)(Bs + (wid*32 + 16 + ln)*40 + qd*8);
    for (int m = 0; m < 4; m++){
      short8 a = *(const short8*)(As + (m*16 + ln)*40 + qd*8);
      acc[m][0] = mfma16(a, b0, acc[m][0]);
      acc[m][1] = mfma16(a, b1, acc[m][1]);
    }
  }
  __syncthreads();
  for (int m = 0; m < 4; m++)
    for (int n2 = 0; n2 < 2; n2++)
      for (int r = 0; r < 4; r++)
        Ys[(m*16 + qd*4 + r)*132 + wid*32 + n2*16 + ln] = acc[m][n2][r];
  __syncthreads();
  {
    int j2 = t & 63, og2 = (t >> 6) * 32;
    int xx = 2*j2 + parx;
    int base = (((b*128 + yy)*128 + xx) << 7) + og2;
    for (int g = 0; g < 4; g++){
      u32 r[4];
      for (int e = 0; e < 4; e++){
        u32 lo = f2b(Ys[j2*132 + og2 + g*8 + 2*e]);
        u32 hi = f2b(Ys[j2*132 + og2 + g*8 + 2*e + 1]);
        r[e] = lo | (hi << 16);
      }
      *(uint4*)(y2 + base + g*8) = make_uint4(r[0], r[1], r[2], r[3]);
    }
  }
  if (t < 128){
    float s = 0.f, ss = 0.f;
    for (int j = 0; j < 64; j++){
      float v = Ys[j*132 + t];
      s += v; ss += v*v;
    }
    atomicAdd(&stats2[t], s);
    atomicAdd(&stats2[128 + t], ss);
  }
}

// ---------------- stage 5: BN2 + ReLU + NHWC->NCHW, f32 out ----------------
__global__ __launch_bounds__(256) void final_kernel(const u16* __restrict__ y2,
                                                    const float2* __restrict__ bn2,
                                                    float* __restrict__ outp){
  __shared__ u16 Ls[128*132];
  __shared__ float2 BNs[128];
  int blk = blockIdx.x;                 // 512 = 4b * 128y
  int yy = blk & 127, b = blk >> 7;
  int t = threadIdx.x;
  if (t < 128) BNs[t] = bn2[t];
  __syncthreads();
  for (int i = 0; i < 8; i++){
    int x = i*16 + (t >> 4);
    int og = (t & 15) * 8;
    uint4 u = *(const uint4*)(y2 + (((b*128 + yy)*128 + x) << 7) + og);
    float f[8];
    f[0] = lo2f(u.x); f[1] = hi2f(u.x); f[2] = lo2f(u.y); f[3] = hi2f(u.y);
    f[4] = lo2f(u.z); f[5] = hi2f(u.z); f[6] = lo2f(u.w); f[7] = hi2f(u.w);
    for (int e = 0; e < 8; e++){
      float2 sc = BNs[og + e];
      Ls[(og + e)*132 + x] = f2b(fmaxf(0.f, fmaf(sc.x, f[e], sc.y)));
    }
  }
  __syncthreads();
  for (int i = 0; i < 16; i++){
    int idx = i*256 + t;
    int o = idx >> 5, xg = (idx & 31) * 4;
    float4 v;
    v.x = b2f(Ls[o*132 + xg + 0]);
    v.y = b2f(Ls[o*132 + xg + 1]);
    v.z = b2f(Ls[o*132 + xg + 2]);
    v.w = b2f(Ls[o*132 + xg + 3]);
    *(float4*)(outp + (((b*128 + o)*128 + yy) << 7) + xg) = v;
  }
}

extern "C" void kernel_launch(void* const* d_in, const int* in_sizes, int n_in,
                              void* d_out, int out_size, void* d_ws, size_t ws_size,
                              hipStream_t stream) {
  const float* x      = (const float*)d_in[0];
  const float* w_off  = (const float*)d_in[1];
  const float* b_off  = (const float*)d_in[2];
  const float* w_dcn  = (const float*)d_in[3];
  const float* b_dcn  = (const float*)d_in[4];
  const float* gamma1 = (const float*)d_in[5];
  const float* beta1  = (const float*)d_in[6];
  const float* w_up   = (const float*)d_in[7];
  const float* gamma2 = (const float*)d_in[8];
  const float* beta2  = (const float*)d_in[9];

  char* ws = (char*)d_ws;
  u16*   xt    = (u16*)(ws + OFF_XT);
  float* om    = (float*)(ws + OFF_OM);
  u16*   yb    = (u16*)(ws + OFF_Y);
  u16*   y2    = (u16*)(ws + OFF_Y2);
  u16*   Boff  = (u16*)(ws + OFF_BOFF);
  u16*   Bdcn  = (u16*)(ws + OFF_BDCN);
  u16*   Bup   = (u16*)(ws + OFF_BUP);
  float* stats = (float*)(ws + OFF_STATS);
  float2* bn1  = (float2*)(ws + OFF_BN1);
  float2* bn2  = (float2*)(ws + OFF_BN2);

  hipMemsetAsync(stats, 0, 2048, stream);
  prep_kernel<<<1152, 256, 0, stream>>>(w_off, w_dcn, w_up, Boff, Bdcn, Bup);
  transpose_kernel<<<1024, 256, 0, stream>>>(x, xt);
  convoff_kernel<<<512, 256, 0, stream>>>(xt, Boff, b_off, om);
  mdcn_kernel<<<512, 256, 0, stream>>>(xt, om, Bdcn, b_dcn, yb, stats);
  bnfin_kernel<<<1, 128, 0, stream>>>(stats, gamma1, beta1, bn1, 1.f/16384.f);
  deconv_kernel<<<1024, 256, 0, stream>>>(yb, bn1, Bup, y2, stats + 256);
  bnfin_kernel<<<1, 128, 0, stream>>>(stats + 256, gamma2, beta2, bn2, 1.f/65536.f);
  final_kernel<<<512, 256, 0, stream>>>(y2, bn2, (float*)d_out);
}